// Round 1
// baseline (842.719 us; speedup 1.0000x reference)
//
#include <hip/hip_runtime.h>
#include <hip/hip_bf16.h>

#define NL 26
#define ND 128
#define NT 64
#define NB 8192
#define WPB 4   // waves per block
#define IPW 2   // items per wave

__device__ __forceinline__ float dot4(float4 a, float4 b, float acc) {
    acc = fmaf(a.x, b.x, acc);
    acc = fmaf(a.y, b.y, acc);
    acc = fmaf(a.z, b.z, acc);
    acc = fmaf(a.w, b.w, acc);
    return acc;
}

__global__ __launch_bounds__(256, 3) void crf_main(
    const float* __restrict__ X, const int* __restrict__ Y,
    const float* __restrict__ P, float* __restrict__ partials)
{
    // W transposed into float4 chunks: W4t[dc*26 + l] = W[l][4dc..4dc+3]
    __shared__ float4 W4t[32 * NL];          // 13312 B
    __shared__ float  TrS[NL * NL];          // 2704 B
    __shared__ __hip_bfloat16 emS[WPB][2 * NT][28];  // 28672 B
    __shared__ float  bp[WPB * IPW];

    const int tid = threadIdx.x;

    const float4* Pf4 = reinterpret_cast<const float4*>(P);
    for (int k = tid; k < 32 * NL; k += 256) {
        int dc = k / NL;
        int l  = k - dc * NL;
        W4t[k] = Pf4[l * 32 + dc];
    }
    for (int k = tid; k < NL * NL; k += 256) TrS[k] = P[NL * ND + k];
    __syncthreads();

    const int warp = tid >> 6;
    const int lane = tid & 63;
    const int half = lane >> 5;          // which of the wave's 2 items
    const int sub  = lane & 31;
    const int subc = (sub < NL) ? sub : (NL - 1);

    const int b = (blockIdx.x * WPB + warp) * IPW + half;

    // ---------------- emission: lane = (item, t), acc over labels ----------
    for (int pass = 0; pass < 2; ++pass) {
        int t = sub + pass * 32;
        const float4* xr = reinterpret_cast<const float4*>(
            X + (((size_t)b) * NT + t) * ND);
        float acc[NL];
        #pragma unroll
        for (int l = 0; l < NL; ++l) acc[l] = 0.f;

        for (int c8 = 0; c8 < 4; ++c8) {
            float4 xb[8];
            #pragma unroll
            for (int j = 0; j < 8; ++j) xb[j] = xr[c8 * 8 + j];
            #pragma unroll
            for (int j = 0; j < 8; ++j) {
                const float4* Wl = &W4t[(c8 * 8 + j) * NL];  // uniform -> LDS broadcast
                #pragma unroll
                for (int l = 0; l < NL; ++l) acc[l] = dot4(xb[j], Wl[l], acc[l]);
            }
        }
        __hip_bfloat16* er = &emS[warp][half * NT + t][0];
        #pragma unroll
        for (int l = 0; l < NL; ++l) er[l] = __float2bfloat16(acc[l]);
    }
    // same wave writes & reads emS[warp] -> no barrier needed (compiler waits lgkmcnt)

    // ---------------- DP: lane = (item, label) -----------------------------
    float Ecol[NL];
    #pragma unroll
    for (int i = 0; i < NL; ++i) Ecol[i] = __expf(TrS[i * NL + subc]);

    const int* yrow = Y + (size_t)b * NT;
    int yprev = yrow[0];
    float em0   = __bfloat162float(emS[warp][half * NT + 0][subc]);
    float alpha = (sub < NL) ? em0 : -__builtin_inff();
    float emsc  = (sub == yprev) ? em0 : 0.f;
    float trsc  = 0.f;

    for (int t = 1; t < NT; ++t) {
        int yt = yrow[t];
        trsc += TrS[yprev * NL + yt];   // uniform per half-group -> broadcast
        yprev = yt;

        float m = alpha;
        #pragma unroll
        for (int k = 16; k >= 1; k >>= 1) m = fmaxf(m, __shfl_xor(m, k));
        float e = __expf(alpha - m);   // lanes >= NL: exp(-inf) = 0
        float s = 0.f;
        #pragma unroll
        for (int i = 0; i < NL; ++i)
            s = fmaf(__shfl(e, i, 32), Ecol[i], s);   // broadcast within half

        float emt = __bfloat162float(emS[warp][half * NT + t][subc]);
        alpha = (sub < NL) ? (m + __logf(s) + emt) : -__builtin_inff();
        emsc += (sub == yt) ? emt : 0.f;
    }

    // logZ
    float m = alpha;
    #pragma unroll
    for (int k = 16; k >= 1; k >>= 1) m = fmaxf(m, __shfl_xor(m, k));
    float e = __expf(alpha - m);
    float s = e;
    #pragma unroll
    for (int k = 16; k >= 1; k >>= 1) s += __shfl_xor(s, k);
    float logZ = m + __logf(s);

    #pragma unroll
    for (int k = 16; k >= 1; k >>= 1) emsc += __shfl_xor(emsc, k);

    float total = emsc + trsc - logZ;
    if (sub == 0) bp[warp * IPW + half] = total;
    __syncthreads();
    if (tid == 0) {
        float sm = 0.f;
        #pragma unroll
        for (int i = 0; i < WPB * IPW; ++i) sm += bp[i];
        partials[blockIdx.x] = sm;
    }
}

__global__ void crf_reduce(const float* __restrict__ partials,
                           float* __restrict__ out, int n) {
    __shared__ float red[256];
    float s = 0.f;
    for (int i = threadIdx.x; i < n; i += 256) s += partials[i];
    red[threadIdx.x] = s;
    __syncthreads();
    for (int k = 128; k >= 1; k >>= 1) {
        if ((int)threadIdx.x < k) red[threadIdx.x] += red[threadIdx.x + k];
        __syncthreads();
    }
    if (threadIdx.x == 0) out[0] = -red[0] / (float)NB;
}

extern "C" void kernel_launch(void* const* d_in, const int* in_sizes, int n_in,
                              void* d_out, int out_size, void* d_ws, size_t ws_size,
                              hipStream_t stream) {
    const float* X = (const float*)d_in[0];
    const int*   Y = (const int*)d_in[1];
    const float* P = (const float*)d_in[2];
    float* out = (float*)d_out;
    float* partials = (float*)d_ws;   // 1024 floats

    const int nblocks = NB / (WPB * IPW);   // 1024
    crf_main<<<nblocks, 256, 0, stream>>>(X, Y, P, partials);
    crf_reduce<<<1, 256, 0, stream>>>(partials, out, nblocks);
}

// Round 3
// 308.673 us; speedup vs baseline: 2.7301x; 2.7301x over previous
//
#include <hip/hip_runtime.h>
#include <hip/hip_fp16.h>
#include <hip/hip_bf16.h>

#define NL 26
#define ND 128
#define NT 64
#define NB 8192
#define NROWS (NB * NT)          // 524288
#define NTILES (NROWS / 16)      // 32768
#define EM_STRIDE 32             // padded labels per row (halfs)
#define EM_BYTES ((size_t)NROWS * EM_STRIDE * sizeof(__half))  // 33554432

typedef __attribute__((ext_vector_type(8))) short bf16x8;
typedef __attribute__((ext_vector_type(4))) float f32x4;

__device__ __forceinline__ uint32_t pk_bf16(float lo, float hi) {
    uint32_t r;
    asm("v_cvt_pk_bf16_f32 %0, %1, %2" : "=v"(r) : "v"(lo), "v"(hi));
    return r;
}

// ROCm 7.2 hip_fp16.h has no __hmax2; use v_pk_max_f16 directly (VOP3P, gfx950-valid)
__device__ __forceinline__ __half2 hmax2(__half2 a, __half2 b) {
    union { __half2 h; uint32_t u; } ua, ub, ur;
    ua.h = a; ub.h = b;
    asm("v_pk_max_f16 %0, %1, %2" : "=v"(ur.u) : "v"(ua.u), "v"(ub.u));
    return ur.h;
}

// ---------------------------------------------------------------------------
// Kernel 1: emission GEMM  em = X @ W^T  (bf16 MFMA), writes exp(em)/16 as fp16
// ---------------------------------------------------------------------------
__global__ __launch_bounds__(256) void crf_em(
    const float* __restrict__ X, const float* __restrict__ P,
    __half* __restrict__ EM)
{
    const int lane = threadIdx.x & 63;
    const int gwave = blockIdx.x * (blockDim.x >> 6) + (threadIdx.x >> 6);
    const int nwaves = gridDim.x * (blockDim.x >> 6);
    const int r16 = lane & 15;   // A row within tile / D col (label)
    const int kq  = lane >> 4;   // k-quarter / D row-quarter

    // B fragments: label n = r16 + 16*h, k = kb*32 + kq*8 + j  -> W[n][k]
    bf16x8 Bf[2][4];
    #pragma unroll
    for (int h = 0; h < 2; ++h) {
        int n = r16 + 16 * h;
        #pragma unroll
        for (int kb = 0; kb < 4; ++kb) {
            float w[8];
            if (n < NL) {
                const float4* wp = reinterpret_cast<const float4*>(P + n * ND + kb * 32 + kq * 8);
                float4 w0 = wp[0], w1 = wp[1];
                w[0]=w0.x; w[1]=w0.y; w[2]=w0.z; w[3]=w0.w;
                w[4]=w1.x; w[5]=w1.y; w[6]=w1.z; w[7]=w1.w;
            } else {
                #pragma unroll
                for (int j = 0; j < 8; ++j) w[j] = 0.f;
            }
            union { uint32_t u[4]; bf16x8 v; } pk;
            pk.u[0] = pk_bf16(w[0], w[1]); pk.u[1] = pk_bf16(w[2], w[3]);
            pk.u[2] = pk_bf16(w[4], w[5]); pk.u[3] = pk_bf16(w[6], w[7]);
            Bf[h][kb] = pk.v;
        }
    }

    const float4* X4 = reinterpret_cast<const float4*>(X);

    for (int tile = gwave; tile < NTILES; tile += nwaves) {
        size_t row = (size_t)tile * 16 + r16;
        float4 xa[4][2];
        #pragma unroll
        for (int kb = 0; kb < 4; ++kb) {
            size_t base = row * 32 + kb * 8 + kq * 2;   // float4 index
            xa[kb][0] = X4[base];
            xa[kb][1] = X4[base + 1];
        }
        f32x4 acc0 = {0.f,0.f,0.f,0.f}, acc1 = {0.f,0.f,0.f,0.f};
        #pragma unroll
        for (int kb = 0; kb < 4; ++kb) {
            union { uint32_t u[4]; bf16x8 v; } A;
            A.u[0] = pk_bf16(xa[kb][0].x, xa[kb][0].y);
            A.u[1] = pk_bf16(xa[kb][0].z, xa[kb][0].w);
            A.u[2] = pk_bf16(xa[kb][1].x, xa[kb][1].y);
            A.u[3] = pk_bf16(xa[kb][1].z, xa[kb][1].w);
            acc0 = __builtin_amdgcn_mfma_f32_16x16x32_bf16(A.v, Bf[0][kb], acc0, 0, 0, 0);
            acc1 = __builtin_amdgcn_mfma_f32_16x16x32_bf16(A.v, Bf[1][kb], acc1, 0, 0, 0);
        }
        // D layout: col = lane&15, row = (lane>>4)*4 + q   [m89-verified]
        size_t obase = (size_t)tile * 16 + kq * 4;
        #pragma unroll
        for (int q = 0; q < 4; ++q) {
            size_t orow = obase + q;
            EM[orow * EM_STRIDE + r16]      = __float2half(__expf(acc0[q]) * 0.0625f);
            EM[orow * EM_STRIDE + r16 + 16] = __float2half(__expf(acc1[q]) * 0.0625f);
        }
    }
}

// ---------------------------------------------------------------------------
// Kernel 2: exp-space forward DP, one item per lane, E in 338 f16x2 VGPRs
// ---------------------------------------------------------------------------
__global__ __launch_bounds__(64, 1) void crf_dp(
    const __half* __restrict__ EM, const int* __restrict__ Y,
    const float* __restrict__ P, float* __restrict__ partials)
{
    __shared__ float TrS[NL * NL];
    const int lane = threadIdx.x;
    for (int k = lane; k < NL * NL; k += 64) TrS[k] = P[NL * ND + k];
    __syncthreads();

    __half2 E2[NL][13];   // E2[i][jp] = (exp(Tr[i][2jp]), exp(Tr[i][2jp+1]))
    #pragma unroll
    for (int i = 0; i < NL; ++i)
        #pragma unroll
        for (int jp = 0; jp < 13; ++jp)
            E2[i][jp] = __floats2half2_rn(__expf(TrS[i * NL + 2 * jp]),
                                          __expf(TrS[i * NL + 2 * jp + 1]));

    const int item = blockIdx.x * 64 + lane;
    const __half*  emh = EM + (size_t)item * NT * EM_STRIDE;
    const __half2* emr = reinterpret_cast<const __half2*>(emh);
    const int* y = Y + (size_t)item * NT;

    __half2 pd[NL];   // p duplicated into both halves
    __half2 pt[13];   // pair accumulators
    float M = 0.f, trsc = 0.f, emsc;

    // ---- t = 0 ----
    int4 yv = *reinterpret_cast<const int4*>(y);
    int yprev = yv.x;
    emsc = __logf(__half2float(emh[yprev]));
    #pragma unroll
    for (int jp = 0; jp < 13; ++jp) pt[jp] = emr[jp];
    {
        __half2 mx = pt[0];
        #pragma unroll
        for (int jp = 1; jp < 13; ++jp) mx = hmax2(mx, pt[jp]);
        float m = fmaxf(__low2float(mx), __high2float(mx));
        M += __logf(m);
        __half2 s2 = __float2half2_rn(1.0f / m);
        #pragma unroll
        for (int jp = 0; jp < 13; ++jp) {
            __half2 v = __hmul2(pt[jp], s2);
            pd[2*jp]   = __half2half2(__low2half(v));
            pd[2*jp+1] = __half2half2(__high2half(v));
        }
    }

    // ---- t = 1..63 ----
    #pragma unroll 1
    for (int tb = 0; tb < 16; ++tb) {
        const int ys0 = yv.x, ys1 = yv.y, ys2 = yv.z, ys3 = yv.w;
        if (tb < 15) yv = *reinterpret_cast<const int4*>(y + (tb + 1) * 4);
        #pragma unroll
        for (int s_ = 0; s_ < 4; ++s_) {
            if (tb == 0 && s_ == 0) continue;
            const int t = tb * 4 + s_;
            const int yt = (s_ == 0) ? ys0 : (s_ == 1) ? ys1 : (s_ == 2) ? ys2 : ys3;
            // loads issued early; the 338-fma block below hides their latency
            __half geh = emh[t * EM_STRIDE + yt];
            __half2 ex[13];
            #pragma unroll
            for (int jp = 0; jp < 13; ++jp) ex[jp] = emr[t * 16 + jp];
            trsc += TrS[yprev * NL + yt];
            yprev = yt;
            // pnew = E^T p   (all operands register-resident)
            #pragma unroll
            for (int jp = 0; jp < 13; ++jp) pt[jp] = __hmul2(pd[0], E2[0][jp]);
            #pragma unroll
            for (int i = 1; i < NL; ++i)
                #pragma unroll
                for (int jp = 0; jp < 13; ++jp)
                    pt[jp] = __hfma2(pd[i], E2[i][jp], pt[jp]);
            // * expem
            #pragma unroll
            for (int jp = 0; jp < 13; ++jp) pt[jp] = __hmul2(pt[jp], ex[jp]);
            // renorm to max=1, track log-scale in M
            __half2 mx = pt[0];
            #pragma unroll
            for (int jp = 1; jp < 13; ++jp) mx = hmax2(mx, pt[jp]);
            float m = fmaxf(__low2float(mx), __high2float(mx));
            M += __logf(m);
            __half2 s2 = __float2half2_rn(1.0f / m);
            #pragma unroll
            for (int jp = 0; jp < 13; ++jp) {
                __half2 v = __hmul2(pt[jp], s2);
                pd[2*jp]   = __half2half2(__low2half(v));
                pd[2*jp+1] = __half2half2(__high2half(v));
            }
            emsc += __logf(__half2float(geh));
        }
    }

    float sum = 0.f;
    #pragma unroll
    for (int i = 0; i < NL; ++i) sum += __low2float(pd[i]);
    float logZ = M + __logf(sum);
    float tot = emsc + trsc - logZ;   // 1/16 scale cancels between emsc and logZ
    #pragma unroll
    for (int k = 32; k >= 1; k >>= 1) tot += __shfl_xor(tot, k);
    if (lane == 0) partials[blockIdx.x] = tot;
}

__global__ void crf_reduce2(const float* __restrict__ partials,
                            float* __restrict__ out, int n) {
    __shared__ float red[256];
    float s = 0.f;
    for (int i = threadIdx.x; i < n; i += 256) s += partials[i];
    red[threadIdx.x] = s;
    __syncthreads();
    for (int k = 128; k >= 1; k >>= 1) {
        if ((int)threadIdx.x < k) red[threadIdx.x] += red[threadIdx.x + k];
        __syncthreads();
    }
    if (threadIdx.x == 0) out[0] = -red[0] / (float)NB;
}

// ---------------------------------------------------------------------------
// Fallback (round-1 kernel, known-correct) if ws is too small for expem
// ---------------------------------------------------------------------------
__device__ __forceinline__ float dot4(float4 a, float4 b, float acc) {
    acc = fmaf(a.x, b.x, acc); acc = fmaf(a.y, b.y, acc);
    acc = fmaf(a.z, b.z, acc); acc = fmaf(a.w, b.w, acc);
    return acc;
}

__global__ __launch_bounds__(256, 3) void crf_main_fb(
    const float* __restrict__ X, const int* __restrict__ Y,
    const float* __restrict__ P, float* __restrict__ partials)
{
    __shared__ float4 W4t[32 * NL];
    __shared__ float  TrS[NL * NL];
    __shared__ __hip_bfloat16 emS[4][2 * NT][28];
    __shared__ float  bp[8];
    const int tid = threadIdx.x;
    const float4* Pf4 = reinterpret_cast<const float4*>(P);
    for (int k = tid; k < 32 * NL; k += 256) {
        int dc = k / NL, l = k - dc * NL;
        W4t[k] = Pf4[l * 32 + dc];
    }
    for (int k = tid; k < NL * NL; k += 256) TrS[k] = P[NL * ND + k];
    __syncthreads();
    const int warp = tid >> 6, lane = tid & 63;
    const int half = lane >> 5, sub = lane & 31;
    const int subc = (sub < NL) ? sub : (NL - 1);
    const int b = (blockIdx.x * 4 + warp) * 2 + half;
    for (int pass = 0; pass < 2; ++pass) {
        int t = sub + pass * 32;
        const float4* xr = reinterpret_cast<const float4*>(X + (((size_t)b) * NT + t) * ND);
        float acc[NL];
        #pragma unroll
        for (int l = 0; l < NL; ++l) acc[l] = 0.f;
        for (int c8 = 0; c8 < 4; ++c8) {
            float4 xb[8];
            #pragma unroll
            for (int j = 0; j < 8; ++j) xb[j] = xr[c8 * 8 + j];
            #pragma unroll
            for (int j = 0; j < 8; ++j) {
                const float4* Wl = &W4t[(c8 * 8 + j) * NL];
                #pragma unroll
                for (int l = 0; l < NL; ++l) acc[l] = dot4(xb[j], Wl[l], acc[l]);
            }
        }
        __hip_bfloat16* er = &emS[warp][half * NT + t][0];
        #pragma unroll
        for (int l = 0; l < NL; ++l) er[l] = __float2bfloat16(acc[l]);
    }
    float Ecol[NL];
    #pragma unroll
    for (int i = 0; i < NL; ++i) Ecol[i] = __expf(TrS[i * NL + subc]);
    const int* yrow = Y + (size_t)b * NT;
    int yprev = yrow[0];
    float em0 = __bfloat162float(emS[warp][half * NT + 0][subc]);
    float alpha = (sub < NL) ? em0 : -__builtin_inff();
    float emsc = (sub == yprev) ? em0 : 0.f;
    float trsc = 0.f;
    for (int t = 1; t < NT; ++t) {
        int yt = yrow[t];
        trsc += TrS[yprev * NL + yt];
        yprev = yt;
        float m = alpha;
        #pragma unroll
        for (int k = 16; k >= 1; k >>= 1) m = fmaxf(m, __shfl_xor(m, k));
        float e = __expf(alpha - m);
        float s = 0.f;
        #pragma unroll
        for (int i = 0; i < NL; ++i) s = fmaf(__shfl(e, i, 32), Ecol[i], s);
        float emt = __bfloat162float(emS[warp][half * NT + t][subc]);
        alpha = (sub < NL) ? (m + __logf(s) + emt) : -__builtin_inff();
        emsc += (sub == yt) ? emt : 0.f;
    }
    float m = alpha;
    #pragma unroll
    for (int k = 16; k >= 1; k >>= 1) m = fmaxf(m, __shfl_xor(m, k));
    float e = __expf(alpha - m);
    float s = e;
    #pragma unroll
    for (int k = 16; k >= 1; k >>= 1) s += __shfl_xor(s, k);
    float logZ = m + __logf(s);
    #pragma unroll
    for (int k = 16; k >= 1; k >>= 1) emsc += __shfl_xor(emsc, k);
    float total = emsc + trsc - logZ;
    if (sub == 0) bp[warp * 2 + half] = total;
    __syncthreads();
    if (tid == 0) {
        float sm = 0.f;
        #pragma unroll
        for (int i = 0; i < 8; ++i) sm += bp[i];
        partials[blockIdx.x] = sm;
    }
}

extern "C" void kernel_launch(void* const* d_in, const int* in_sizes, int n_in,
                              void* d_out, int out_size, void* d_ws, size_t ws_size,
                              hipStream_t stream) {
    const float* X = (const float*)d_in[0];
    const int*   Y = (const int*)d_in[1];
    const float* P = (const float*)d_in[2];
    float* out = (float*)d_out;

    if (ws_size >= EM_BYTES + 1024) {
        __half* EM = (__half*)d_ws;
        float* partials = (float*)((char*)d_ws + EM_BYTES);   // 128 floats
        crf_em<<<2048, 256, 0, stream>>>(X, P, EM);
        crf_dp<<<128, 64, 0, stream>>>(EM, Y, P, partials);
        crf_reduce2<<<1, 256, 0, stream>>>(partials, out, 128);
    } else {
        float* partials = (float*)d_ws;   // 1024 floats
        crf_main_fb<<<1024, 256, 0, stream>>>(X, Y, P, partials);
        crf_reduce2<<<1, 256, 0, stream>>>(partials, out, 1024);
    }
}

// Round 4
// 128.331 us; speedup vs baseline: 6.5667x; 2.4053x over previous
//
#include <hip/hip_runtime.h>
#include <hip/hip_fp16.h>
#include <hip/hip_bf16.h>

#define NL 26
#define ND 128
#define NT 64
#define NB 8192
#define NROWS (NB * NT)          // 524288
#define NTILES (NROWS / 16)      // 32768
#define EM_STRIDE 32             // padded labels per row (halfs)
#define EM_BYTES ((size_t)NROWS * EM_STRIDE * sizeof(__half))  // 33554432

typedef __attribute__((ext_vector_type(8))) short bf16x8;
typedef __attribute__((ext_vector_type(4))) float f32x4;

__device__ __forceinline__ uint32_t pk_bf16(float lo, float hi) {
    uint32_t r;
    asm("v_cvt_pk_bf16_f32 %0, %1, %2" : "=v"(r) : "v"(lo), "v"(hi));
    return r;
}

// ---------------------------------------------------------------------------
// Kernel 1: emission GEMM  em = X @ W^T  (bf16 MFMA), writes exp(em)/16 as fp16
// ---------------------------------------------------------------------------
__global__ __launch_bounds__(256) void crf_em(
    const float* __restrict__ X, const float* __restrict__ P,
    __half* __restrict__ EM)
{
    const int lane = threadIdx.x & 63;
    const int gwave = blockIdx.x * (blockDim.x >> 6) + (threadIdx.x >> 6);
    const int nwaves = gridDim.x * (blockDim.x >> 6);
    const int r16 = lane & 15;   // A row within tile / D col (label)
    const int kq  = lane >> 4;   // k-quarter / D row-quarter

    // B fragments: label n = r16 + 16*h, k = kb*32 + kq*8 + j  -> W[n][k]
    bf16x8 Bf[2][4];
    #pragma unroll
    for (int h = 0; h < 2; ++h) {
        int n = r16 + 16 * h;
        #pragma unroll
        for (int kb = 0; kb < 4; ++kb) {
            float w[8];
            if (n < NL) {
                const float4* wp = reinterpret_cast<const float4*>(P + n * ND + kb * 32 + kq * 8);
                float4 w0 = wp[0], w1 = wp[1];
                w[0]=w0.x; w[1]=w0.y; w[2]=w0.z; w[3]=w0.w;
                w[4]=w1.x; w[5]=w1.y; w[6]=w1.z; w[7]=w1.w;
            } else {
                #pragma unroll
                for (int j = 0; j < 8; ++j) w[j] = 0.f;
            }
            union { uint32_t u[4]; bf16x8 v; } pk;
            pk.u[0] = pk_bf16(w[0], w[1]); pk.u[1] = pk_bf16(w[2], w[3]);
            pk.u[2] = pk_bf16(w[4], w[5]); pk.u[3] = pk_bf16(w[6], w[7]);
            Bf[h][kb] = pk.v;
        }
    }

    const float4* X4 = reinterpret_cast<const float4*>(X);

    for (int tile = gwave; tile < NTILES; tile += nwaves) {
        size_t row = (size_t)tile * 16 + r16;
        float4 xa[4][2];
        #pragma unroll
        for (int kb = 0; kb < 4; ++kb) {
            size_t base = row * 32 + kb * 8 + kq * 2;   // float4 index
            xa[kb][0] = X4[base];
            xa[kb][1] = X4[base + 1];
        }
        f32x4 acc0 = {0.f,0.f,0.f,0.f}, acc1 = {0.f,0.f,0.f,0.f};
        #pragma unroll
        for (int kb = 0; kb < 4; ++kb) {
            union { uint32_t u[4]; bf16x8 v; } A;
            A.u[0] = pk_bf16(xa[kb][0].x, xa[kb][0].y);
            A.u[1] = pk_bf16(xa[kb][0].z, xa[kb][0].w);
            A.u[2] = pk_bf16(xa[kb][1].x, xa[kb][1].y);
            A.u[3] = pk_bf16(xa[kb][1].z, xa[kb][1].w);
            acc0 = __builtin_amdgcn_mfma_f32_16x16x32_bf16(A.v, Bf[0][kb], acc0, 0, 0, 0);
            acc1 = __builtin_amdgcn_mfma_f32_16x16x32_bf16(A.v, Bf[1][kb], acc1, 0, 0, 0);
        }
        // D layout: col = lane&15, row = (lane>>4)*4 + q   [m89-verified]
        size_t obase = (size_t)tile * 16 + kq * 4;
        #pragma unroll
        for (int q = 0; q < 4; ++q) {
            size_t orow = obase + q;
            EM[orow * EM_STRIDE + r16]      = __float2half(__expf(acc0[q]) * 0.0625f);
            EM[orow * EM_STRIDE + r16 + 16] = __float2half(__expf(acc1[q]) * 0.0625f);
        }
    }
}

// ---------------------------------------------------------------------------
// Kernel 2: exp-space forward DP.
// lane = (item-half, label j); 2 items per wave; 4 waves/block -> 8 items.
// p broadcast via uniform ds_read_b128 (conflict-free LDS broadcast).
// E columns register-resident (28 f32, uniform per lane -> no pressure).
// Renorm by half-wave max every 4 steps; exact log-scale tracked in M.
// ---------------------------------------------------------------------------
#define DP_IPB 8   // items per block (4 waves x 2 halves)

__global__ __launch_bounds__(256, 4) void crf_dp2(
    const __half* __restrict__ EM, const int* __restrict__ Y,
    const float* __restrict__ P, float* __restrict__ partials)
{
    __shared__ float TrS[NL * NL];
    __shared__ float pbuf[4][2][32];   // [wave][half][label-slot]
    __shared__ float itot[DP_IPB];

    const int tid = threadIdx.x;
    for (int k = tid; k < NL * NL; k += 256) TrS[k] = P[NL * ND + k];
    __syncthreads();

    const int warp = tid >> 6;
    const int lane = tid & 63;
    const int half = lane >> 5;
    const int j    = lane & 31;
    const bool act = (j < NL);

    const int item = blockIdx.x * DP_IPB + warp * 2 + half;

    // E columns: Ecol[i] = exp(Tr[i][j]); padded to 28 with zeros
    float Ecol[28];
    #pragma unroll
    for (int i = 0; i < NL; ++i) Ecol[i] = act ? __expf(TrS[i * NL + j]) : 0.f;
    Ecol[26] = 0.f; Ecol[27] = 0.f;

    const __half* em = EM + (size_t)item * NT * EM_STRIDE;
    const int*    y  = Y + (size_t)item * NT;
    float* myp = pbuf[warp][half];

    // ---- t = 0 ----
    int yprev = y[0];
    float p = act ? __half2float(em[j]) : 0.f;           // pe_0
    float emsc = __logf(__half2float(em[yprev]));
    float trsc = 0.f, M = 0.f;

    // ---- t = 1..63 ----
    for (int t = 1; t < NT; ++t) {
        myp[j] = p;                       // includes zeros for j>=26
        const int yt = y[t];
        trsc += TrS[yprev * NL + yt];
        yprev = yt;

        // acc = sum_i p[i] * E[i][j]  via 7 uniform float4 broadcasts
        const float4* pp4 = reinterpret_cast<const float4*>(myp);
        float acc0 = 0.f, acc1 = 0.f;
        #pragma unroll
        for (int ip = 0; ip < 7; ++ip) {
            float4 q = pp4[ip];
            acc0 = fmaf(q.x, Ecol[4 * ip],     acc0);
            acc1 = fmaf(q.y, Ecol[4 * ip + 1], acc1);
            acc0 = fmaf(q.z, Ecol[4 * ip + 2], acc0);
            acc1 = fmaf(q.w, Ecol[4 * ip + 3], acc1);
        }
        float pe = act ? __half2float(em[t * EM_STRIDE + j]) : 0.f;
        p = (acc0 + acc1) * pe;
        emsc += __logf(__half2float(em[t * EM_STRIDE + yt]));

        if ((t & 3) == 0) {               // renorm every 4 steps
            float m = p;
            #pragma unroll
            for (int k = 16; k >= 1; k >>= 1) m = fmaxf(m, __shfl_xor(m, k));
            M += __logf(m);
            p *= (1.0f / m);
        }
    }

    // logZ = M + log(sum_j p[j])
    float s = p;
    #pragma unroll
    for (int k = 16; k >= 1; k >>= 1) s += __shfl_xor(s, k);
    float logZ = M + __logf(s);
    float tot = emsc + trsc - logZ;       // 1/16 scale cancels emsc vs logZ

    if (j == 0) itot[warp * 2 + half] = tot;
    __syncthreads();
    if (tid == 0) {
        float sm = 0.f;
        #pragma unroll
        for (int i = 0; i < DP_IPB; ++i) sm += itot[i];
        partials[blockIdx.x] = sm;
    }
}

__global__ void crf_reduce2(const float* __restrict__ partials,
                            float* __restrict__ out, int n) {
    __shared__ float red[256];
    float s = 0.f;
    for (int i = threadIdx.x; i < n; i += 256) s += partials[i];
    red[threadIdx.x] = s;
    __syncthreads();
    for (int k = 128; k >= 1; k >>= 1) {
        if ((int)threadIdx.x < k) red[threadIdx.x] += red[threadIdx.x + k];
        __syncthreads();
    }
    if (threadIdx.x == 0) out[0] = -red[0] / (float)NB;
}

// ---------------------------------------------------------------------------
// Fallback (round-1 kernel, known-correct) if ws is too small for expem
// ---------------------------------------------------------------------------
__device__ __forceinline__ float dot4(float4 a, float4 b, float acc) {
    acc = fmaf(a.x, b.x, acc); acc = fmaf(a.y, b.y, acc);
    acc = fmaf(a.z, b.z, acc); acc = fmaf(a.w, b.w, acc);
    return acc;
}

__global__ __launch_bounds__(256, 3) void crf_main_fb(
    const float* __restrict__ X, const int* __restrict__ Y,
    const float* __restrict__ P, float* __restrict__ partials)
{
    __shared__ float4 W4t[32 * NL];
    __shared__ float  TrS[NL * NL];
    __shared__ __hip_bfloat16 emS[4][2 * NT][28];
    __shared__ float  bp[8];
    const int tid = threadIdx.x;
    const float4* Pf4 = reinterpret_cast<const float4*>(P);
    for (int k = tid; k < 32 * NL; k += 256) {
        int dc = k / NL, l = k - dc * NL;
        W4t[k] = Pf4[l * 32 + dc];
    }
    for (int k = tid; k < NL * NL; k += 256) TrS[k] = P[NL * ND + k];
    __syncthreads();
    const int warp = tid >> 6, lane = tid & 63;
    const int half = lane >> 5, sub = lane & 31;
    const int subc = (sub < NL) ? sub : (NL - 1);
    const int b = (blockIdx.x * 4 + warp) * 2 + half;
    for (int pass = 0; pass < 2; ++pass) {
        int t = sub + pass * 32;
        const float4* xr = reinterpret_cast<const float4*>(X + (((size_t)b) * NT + t) * ND);
        float acc[NL];
        #pragma unroll
        for (int l = 0; l < NL; ++l) acc[l] = 0.f;
        for (int c8 = 0; c8 < 4; ++c8) {
            float4 xb[8];
            #pragma unroll
            for (int j = 0; j < 8; ++j) xb[j] = xr[c8 * 8 + j];
            #pragma unroll
            for (int j = 0; j < 8; ++j) {
                const float4* Wl = &W4t[(c8 * 8 + j) * NL];
                #pragma unroll
                for (int l = 0; l < NL; ++l) acc[l] = dot4(xb[j], Wl[l], acc[l]);
            }
        }
        __hip_bfloat16* er = &emS[warp][half * NT + t][0];
        #pragma unroll
        for (int l = 0; l < NL; ++l) er[l] = __float2bfloat16(acc[l]);
    }
    float Ecol[NL];
    #pragma unroll
    for (int i = 0; i < NL; ++i) Ecol[i] = __expf(TrS[i * NL + subc]);
    const int* yrow = Y + (size_t)b * NT;
    int yprev = yrow[0];
    float em0 = __bfloat162float(emS[warp][half * NT + 0][subc]);
    float alpha = (sub < NL) ? em0 : -__builtin_inff();
    float emsc = (sub == yprev) ? em0 : 0.f;
    float trsc = 0.f;
    for (int t = 1; t < NT; ++t) {
        int yt = yrow[t];
        trsc += TrS[yprev * NL + yt];
        yprev = yt;
        float m = alpha;
        #pragma unroll
        for (int k = 16; k >= 1; k >>= 1) m = fmaxf(m, __shfl_xor(m, k));
        float e = __expf(alpha - m);
        float s = 0.f;
        #pragma unroll
        for (int i = 0; i < NL; ++i) s = fmaf(__shfl(e, i, 32), Ecol[i], s);
        float emt = __bfloat162float(emS[warp][half * NT + t][subc]);
        alpha = (sub < NL) ? (m + __logf(s) + emt) : -__builtin_inff();
        emsc += (sub == yt) ? emt : 0.f;
    }
    float m = alpha;
    #pragma unroll
    for (int k = 16; k >= 1; k >>= 1) m = fmaxf(m, __shfl_xor(m, k));
    float e = __expf(alpha - m);
    float s = e;
    #pragma unroll
    for (int k = 16; k >= 1; k >>= 1) s += __shfl_xor(s, k);
    float logZ = m + __logf(s);
    #pragma unroll
    for (int k = 16; k >= 1; k >>= 1) emsc += __shfl_xor(emsc, k);
    float total = emsc + trsc - logZ;
    if (sub == 0) bp[warp * 2 + half] = total;
    __syncthreads();
    if (tid == 0) {
        float sm = 0.f;
        #pragma unroll
        for (int i = 0; i < 8; ++i) sm += bp[i];
        partials[blockIdx.x] = sm;
    }
}

extern "C" void kernel_launch(void* const* d_in, const int* in_sizes, int n_in,
                              void* d_out, int out_size, void* d_ws, size_t ws_size,
                              hipStream_t stream) {
    const float* X = (const float*)d_in[0];
    const int*   Y = (const int*)d_in[1];
    const float* P = (const float*)d_in[2];
    float* out = (float*)d_out;

    if (ws_size >= EM_BYTES + 4096) {
        __half* EM = (__half*)d_ws;
        float* partials = (float*)((char*)d_ws + EM_BYTES);   // 1024 floats
        crf_em<<<2048, 256, 0, stream>>>(X, P, EM);
        crf_dp2<<<NB / DP_IPB, 256, 0, stream>>>(EM, Y, P, partials);
        crf_reduce2<<<1, 256, 0, stream>>>(partials, out, NB / DP_IPB);
    } else {
        float* partials = (float*)d_ws;   // 1024 floats
        crf_main_fb<<<1024, 256, 0, stream>>>(X, Y, P, partials);
        crf_reduce2<<<1, 256, 0, stream>>>(partials, out, 1024);
    }
}

// Round 5
// 85.468 us; speedup vs baseline: 9.8601x; 1.5015x over previous
//
#include <hip/hip_runtime.h>
#include <hip/hip_fp16.h>
#include <hip/hip_bf16.h>

#define NL 26
#define ND 128
#define NT 64
#define NB 8192

typedef __attribute__((ext_vector_type(8))) short bf16x8;
typedef __attribute__((ext_vector_type(4))) float f32x4;

__device__ __forceinline__ uint32_t pk_bf16(float lo, float hi) {
    uint32_t r;
    asm("v_cvt_pk_bf16_f32 %0, %1, %2" : "=v"(r) : "v"(lo), "v"(hi));
    return r;
}

// ---------------------------------------------------------------------------
// Fused kernel: each wave owns 2 items end-to-end.
//  Phase A: emission GEMM (bf16 MFMA) for the wave's 2 items (128 rows),
//           exp(em)/16 as fp16 into a wave-private 8 KB LDS region.
//  Phase B: exp-space forward DP (validated dp2 structure) reading em from LDS.
// No inter-phase barrier: same-wave DS ops are in-order.
// ---------------------------------------------------------------------------
__global__ __launch_bounds__(256, 4) void crf_fused(
    const float* __restrict__ X, const int* __restrict__ Y,
    const float* __restrict__ P, float* __restrict__ partials)
{
    __shared__ float TrS[NL * NL];                  // 2704 B
    __shared__ __half emS[4][2 * NT][32];           // 32 KB, [wave][lr][label]
    __shared__ alignas(16) float pbuf[4][2][32];    // 1 KB
    __shared__ float itot[8];

    const int tid = threadIdx.x;
    for (int k = tid; k < NL * NL; k += 256) TrS[k] = P[NL * ND + k];
    __syncthreads();

    const int warp = tid >> 6;
    const int lane = tid & 63;
    const int r16  = lane & 15;   // A-row in tile / D col (label)
    const int kq   = lane >> 4;   // k-quarter / D row-quarter

    // ---- W fragments: label n = r16 + 16*h, k = kb*32 + kq*8 + j ----
    bf16x8 Bf[2][4];
    #pragma unroll
    for (int h = 0; h < 2; ++h) {
        int n = r16 + 16 * h;
        #pragma unroll
        for (int kb = 0; kb < 4; ++kb) {
            float w[8];
            if (n < NL) {
                const float4* wp = reinterpret_cast<const float4*>(P + n * ND + kb * 32 + kq * 8);
                float4 w0 = wp[0], w1 = wp[1];
                w[0]=w0.x; w[1]=w0.y; w[2]=w0.z; w[3]=w0.w;
                w[4]=w1.x; w[5]=w1.y; w[6]=w1.z; w[7]=w1.w;
            } else {
                #pragma unroll
                for (int jj = 0; jj < 8; ++jj) w[jj] = 0.f;
            }
            union { uint32_t u[4]; bf16x8 v; } pk;
            pk.u[0] = pk_bf16(w[0], w[1]); pk.u[1] = pk_bf16(w[2], w[3]);
            pk.u[2] = pk_bf16(w[4], w[5]); pk.u[3] = pk_bf16(w[6], w[7]);
            Bf[h][kb] = pk.v;
        }
    }

    const int item0 = blockIdx.x * 8 + warp * 2;
    const float4* X4 = reinterpret_cast<const float4*>(X);
    const size_t rowbase = (size_t)item0 * NT;   // 128 consecutive rows

    // ---- phase A: 8 tiles of 16 rows ----
    for (int tt = 0; tt < 8; ++tt) {
        size_t row = rowbase + tt * 16 + r16;
        float4 xa[4][2];
        #pragma unroll
        for (int kb = 0; kb < 4; ++kb) {
            size_t base = row * 32 + kb * 8 + kq * 2;   // float4 index
            xa[kb][0] = X4[base];
            xa[kb][1] = X4[base + 1];
        }
        f32x4 acc0 = {0.f,0.f,0.f,0.f}, acc1 = {0.f,0.f,0.f,0.f};
        #pragma unroll
        for (int kb = 0; kb < 4; ++kb) {
            union { uint32_t u[4]; bf16x8 v; } A;
            A.u[0] = pk_bf16(xa[kb][0].x, xa[kb][0].y);
            A.u[1] = pk_bf16(xa[kb][0].z, xa[kb][0].w);
            A.u[2] = pk_bf16(xa[kb][1].x, xa[kb][1].y);
            A.u[3] = pk_bf16(xa[kb][1].z, xa[kb][1].w);
            acc0 = __builtin_amdgcn_mfma_f32_16x16x32_bf16(A.v, Bf[0][kb], acc0, 0, 0, 0);
            acc1 = __builtin_amdgcn_mfma_f32_16x16x32_bf16(A.v, Bf[1][kb], acc1, 0, 0, 0);
        }
        // D layout: col = lane&15, row = kq*4 + q   [m89-verified]
        int lr = tt * 16 + kq * 4;
        #pragma unroll
        for (int q = 0; q < 4; ++q) {
            emS[warp][lr + q][r16]      = __float2half(__expf(acc0[q]) * 0.0625f);
            emS[warp][lr + q][r16 + 16] = __float2half(__expf(acc1[q]) * 0.0625f);
        }
    }

    // ---- phase B: DP, half-wave per item ----
    const int half = lane >> 5;
    const int j    = lane & 31;
    const bool act = (j < NL);

    float Ecol[28];
    #pragma unroll
    for (int i = 0; i < NL; ++i) Ecol[i] = act ? __expf(TrS[i * NL + j]) : 0.f;
    Ecol[26] = 0.f; Ecol[27] = 0.f;

    const __half* em = &emS[warp][half * NT][0];     // [64][32]
    const int* y = Y + (size_t)(item0 + half) * NT;
    float* myp = pbuf[warp][half];

    int yprev = y[0];
    float p = act ? __half2float(em[j]) : 0.f;       // pe_0
    float emsc = __logf(__half2float(em[yprev]));
    float trsc = 0.f, M = 0.f;

    for (int t = 1; t < NT; ++t) {
        myp[j] = p;                                  // zeros for j>=26
        const int yt = y[t];
        trsc += TrS[yprev * NL + yt];
        yprev = yt;

        const float4* pp4 = reinterpret_cast<const float4*>(myp);
        float a0 = 0.f, a1 = 0.f;
        #pragma unroll
        for (int ip = 0; ip < 7; ++ip) {
            float4 q4 = pp4[ip];                     // uniform -> LDS broadcast
            a0 = fmaf(q4.x, Ecol[4 * ip],     a0);
            a1 = fmaf(q4.y, Ecol[4 * ip + 1], a1);
            a0 = fmaf(q4.z, Ecol[4 * ip + 2], a0);
            a1 = fmaf(q4.w, Ecol[4 * ip + 3], a1);
        }
        float pe = act ? __half2float(em[t * 32 + j]) : 0.f;
        p = (a0 + a1) * pe;
        emsc += __logf(__half2float(em[t * 32 + yt]));

        if ((t & 3) == 0) {                          // renorm every 4 steps
            float m = p;
            #pragma unroll
            for (int k = 16; k >= 1; k >>= 1) m = fmaxf(m, __shfl_xor(m, k));
            M += __logf(m);
            p *= (1.0f / m);
        }
    }

    float s = p;
    #pragma unroll
    for (int k = 16; k >= 1; k >>= 1) s += __shfl_xor(s, k);
    float logZ = M + __logf(s);
    float tot = emsc + trsc - logZ;                  // 1/16 scale cancels

    if (j == 0) itot[warp * 2 + half] = tot;
    __syncthreads();
    if (tid == 0) {
        float sm = 0.f;
        #pragma unroll
        for (int i = 0; i < 8; ++i) sm += itot[i];
        partials[blockIdx.x] = sm;
    }
}

__global__ void crf_reduce2(const float* __restrict__ partials,
                            float* __restrict__ out, int n) {
    __shared__ float red[256];
    float s = 0.f;
    for (int i = threadIdx.x; i < n; i += 256) s += partials[i];
    red[threadIdx.x] = s;
    __syncthreads();
    for (int k = 128; k >= 1; k >>= 1) {
        if ((int)threadIdx.x < k) red[threadIdx.x] += red[threadIdx.x + k];
        __syncthreads();
    }
    if (threadIdx.x == 0) out[0] = -red[0] / (float)NB;
}

extern "C" void kernel_launch(void* const* d_in, const int* in_sizes, int n_in,
                              void* d_out, int out_size, void* d_ws, size_t ws_size,
                              hipStream_t stream) {
    const float* X = (const float*)d_in[0];
    const int*   Y = (const int*)d_in[1];
    const float* P = (const float*)d_in[2];
    float* out = (float*)d_out;
    float* partials = (float*)d_ws;   // 1024 floats

    crf_fused<<<NB / 8, 256, 0, stream>>>(X, Y, P, partials);
    crf_reduce2<<<1, 256, 0, stream>>>(partials, out, NB / 8);
}